// Round 7
// baseline (134.208 us; speedup 1.0000x reference)
//
#include <hip/hip_runtime.h>
#include <hip/hip_fp16.h>
#include <math.h>

#define Bn 128
#define Nn 128
#define Ln 64
#define Pn 30
#define PG 10

// ws layout in 4-byte words:
#define TOFF  0        // tab:    [P][N*N] uint32 = half2{logsig(-l), l} : 491520 words
#define BOFF  491520   // Bpack:  [P][N][4] uint32 bitrows of (mask&Adj): 15360 words
#define VOFFW 506880   // validf: [P][N] float                          : 3840 words
#define ROFF  510720   // rec:    [B][P] float                          : 3840 words

// ---------------- K1: table build (GEMM + logsig) + bit-pack ----------------
__global__ __launch_bounds__(256) void k_prep(const float* __restrict__ mu,
                                              const float* __restrict__ logstd,
                                              const float* __restrict__ eps,
                                              const float* __restrict__ W,
                                              const int* __restrict__ Adj,
                                              const int* __restrict__ nm,
                                              float* __restrict__ ws) {
    int blk = blockIdx.x, t = threadIdx.x;
    if (blk < 192) {
        // table blocks: 64 uv-chunks x 3 p-groups of PG=10 graphs
        int chunk = blk & 63, pg = blk >> 6;
        __shared__ float zs[PG][Ln];   // 256B per row -> float4-aligned
        for (int idx = t; idx < PG * Ln; idx += 256) {
            int g = pg * PG * Ln + idx;      // graph index == batch index for b < P
            zs[idx / Ln][idx % Ln] = mu[g] + eps[g] * __expf(logstd[g]);
        }
        __syncthreads();
        int uv = chunk * 256 + t;
        float acc[PG];
#pragma unroll
        for (int q = 0; q < PG; q++) acc[q] = 0.f;

        const float4* zs4 = (const float4*)&zs[0][0];   // [PG][16]
        // 8 batches of 8 W loads in flight; FMA order stays k-ascending
        for (int kb = 0; kb < 8; ++kb) {
            float wv[8];
#pragma unroll
            for (int j = 0; j < 8; ++j)
                wv[j] = W[(kb * 8 + j) * (Nn * Nn) + uv];
#pragma unroll
            for (int q = 0; q < PG; q++) {
                float4 z0 = zs4[q * 16 + kb * 2];
                float4 z1 = zs4[q * 16 + kb * 2 + 1];
                acc[q] = fmaf(z0.x, wv[0], acc[q]);
                acc[q] = fmaf(z0.y, wv[1], acc[q]);
                acc[q] = fmaf(z0.z, wv[2], acc[q]);
                acc[q] = fmaf(z0.w, wv[3], acc[q]);
                acc[q] = fmaf(z1.x, wv[4], acc[q]);
                acc[q] = fmaf(z1.y, wv[5], acc[q]);
                acc[q] = fmaf(z1.z, wv[6], acc[q]);
                acc[q] = fmaf(z1.w, wv[7], acc[q]);
            }
        }
        uint32_t* tab = (uint32_t*)ws;
#pragma unroll
        for (int q = 0; q < PG; q++) {
            int p = pg * PG + q;
            float l = acc[q];
            float nl = -l;
            float lsneg = (nl < 0.f) ? (nl - log1pf(__expf(nl))) : (-log1pf(__expf(-nl)));
            __half2 h = __floats2half2_rn(lsneg, l);
            tab[p * (Nn * Nn) + uv] = *(uint32_t*)&h;
        }
    } else {
        // bit-pack: 2 blocks per graph, one 32-bit word per thread, no ballot chain
        int pb = blk - 192;
        int p  = pb >> 1;
        int rh = pb & 1;                 // row half: rows rh*64 .. rh*64+63
        __shared__ float    val_s[Nn];
        __shared__ uint32_t vb_s[4];     // valid bits, word w covers cols w*32..+31
        if (t < Nn) {
            float v = (float)nm[p * Nn * Nn + t * Nn + t];  // diag = valid[t]
            val_s[t] = v;
            ws[VOFFW + p * Nn + t] = v;  // both halves write identical values
        }
        __syncthreads();
        if (t < 128) {                   // waves 0,1: wave-uniform branch
            unsigned long long m = __ballot(val_s[t] != 0.f);
            if ((t & 63) == 0) {
                int wv2 = t >> 6;
                vb_s[wv2 * 2]     = (uint32_t)m;
                vb_s[wv2 * 2 + 1] = (uint32_t)(m >> 32);
            }
        }
        __syncthreads();

        int r = t >> 2;                  // local row 0..63
        int w = t & 3;                   // word 0..3
        int i = rh * 64 + r;
        uint32_t bits = 0;
        if (val_s[i] != 0.f) {
            const int4* av = (const int4*)(Adj + p * Nn * Nn + i * Nn + w * 32);
            int4 a[8];
#pragma unroll
            for (int c = 0; c < 8; ++c) a[c] = av[c];   // 8 independent 16B loads
#pragma unroll
            for (int c = 0; c < 8; ++c) {
                bits |= (a[c].x != 0 ? 1u : 0u) << (c * 4 + 0);
                bits |= (a[c].y != 0 ? 1u : 0u) << (c * 4 + 1);
                bits |= (a[c].z != 0 ? 1u : 0u) << (c * 4 + 2);
                bits |= (a[c].w != 0 ? 1u : 0u) << (c * 4 + 3);
            }
            bits &= vb_s[w];
        }
        ((uint32_t*)ws)[BOFF + p * Nn * 4 + i * 4 + w] = bits;
    }
}

// ---------------- K2: hot loop, 4 batches/block, readlane row metadata ----------------
__global__ __launch_bounds__(256) void k_main(const int* __restrict__ perms,
                                              const float* __restrict__ ws,
                                              float* __restrict__ rec) {
    int p  = blockIdx.x >> 5;           // consecutive blocks share per-p data in L2
    int bb = blockIdx.x & 31;
    int b_base = bb * 4;
    int t = threadIdx.x;

    __shared__ int      inv_s[4][Nn];
    __shared__ uint32_t B_s[Nn * 4];
    __shared__ float    valid_s[Nn];
    __shared__ float    redw[4][4];

    // load 4 perms (512 entries) + bits (512 words) + valid (128 floats)
    {
        int idx0 = t, idx1 = t + 256;
        int ba0 = idx0 >> 7, i0 = idx0 & 127;
        int ba1 = idx1 >> 7, i1 = idx1 & 127;
        inv_s[ba0][perms[((b_base + ba0) * Pn + p) * Nn + i0]] = i0;
        inv_s[ba1][perms[((b_base + ba1) * Pn + p) * Nn + i1]] = i1;
        const uint32_t* Bp = (const uint32_t*)ws + BOFF + p * Nn * 4;
        B_s[t]       = Bp[t];
        B_s[256 + t] = Bp[256 + t];
        if (t < Nn) valid_s[t] = ws[VOFFW + p * Nn + t];
    }
    __syncthreads();

    int lane = t & 63;
    int wid  = t >> 6;
    int swid = __builtin_amdgcn_readfirstlane(wid);
    int v0 = 2 * lane, v1 = v0 + 1;

    // loop-invariant per (batch, slot) coordinates + row metadata in registers
    float wv0[4], wv1[4];
    int   a0[4], sh0[4], a1[4], sh1[4];
    int   iu_lo[4], iu_hi[4], vu_lo[4], vu_hi[4];
#pragma unroll
    for (int b = 0; b < 4; ++b) {
        int j0 = inv_s[b][v0], j1 = inv_s[b][v1];
        wv0[b] = valid_s[j0];  wv1[b] = valid_s[j1];
        a0[b] = j0 >> 5; sh0[b] = j0 & 31;
        a1[b] = j1 >> 5; sh1[b] = j1 & 31;
        int il = inv_s[b][lane];       // row metadata: lane L holds row u=L (lo) / 64+L (hi)
        int ih = inv_s[b][64 + lane];
        iu_lo[b] = il; iu_hi[b] = ih;
        vu_lo[b] = __float_as_int(valid_s[il]);
        vu_hi[b] = __float_as_int(valid_s[ih]);
    }

    const uint2* tab2 = (const uint2*)((const uint32_t*)ws + p * (Nn * Nn));
    float acc[4] = {0.f, 0.f, 0.f, 0.f};

    // ---- rows u in [0,64): metadata via readlane from *_lo ----
#pragma unroll
    for (int it = 0; it < 16; ++it) {
        int u = it * 4 + swid;                      // wave-uniform scalar
        uint2 hw = tab2[u * (Nn / 2) + lane];       // coalesced 8B/lane
        float2 f0 = __half22float2(*(__half2*)&hw.x);
        float2 f1 = __half22float2(*(__half2*)&hw.y);
#pragma unroll
        for (int b = 0; b < 4; ++b) {
            int   si  = __builtin_amdgcn_readlane(iu_lo[b], u);
            float swu = __int_as_float(__builtin_amdgcn_readlane(vu_lo[b], u));
            float tmp = fmaf(wv1[b], f1.x, wv0[b] * f0.x);
            acc[b] = fmaf(swu, tmp, acc[b]);
            uint32_t r0 = B_s[si * 4 + a0[b]];
            uint32_t r1 = B_s[si * 4 + a1[b]];
            acc[b] += ((r0 >> sh0[b]) & 1u) ? f0.y : 0.0f;
            acc[b] += ((r1 >> sh1[b]) & 1u) ? f1.y : 0.0f;
        }
    }
    // ---- rows u in [64,128): metadata via readlane from *_hi ----
#pragma unroll
    for (int it = 0; it < 16; ++it) {
        int u = it * 4 + swid;                      // in [0,64): actual row = 64+u
        uint2 hw = tab2[(64 + u) * (Nn / 2) + lane];
        float2 f0 = __half22float2(*(__half2*)&hw.x);
        float2 f1 = __half22float2(*(__half2*)&hw.y);
#pragma unroll
        for (int b = 0; b < 4; ++b) {
            int   si  = __builtin_amdgcn_readlane(iu_hi[b], u);
            float swu = __int_as_float(__builtin_amdgcn_readlane(vu_hi[b], u));
            float tmp = fmaf(wv1[b], f1.x, wv0[b] * f0.x);
            acc[b] = fmaf(swu, tmp, acc[b]);
            uint32_t r0 = B_s[si * 4 + a0[b]];
            uint32_t r1 = B_s[si * 4 + a1[b]];
            acc[b] += ((r0 >> sh0[b]) & 1u) ? f0.y : 0.0f;
            acc[b] += ((r1 >> sh1[b]) & 1u) ? f1.y : 0.0f;
        }
    }

    // wave reduce all 4 accumulators
#pragma unroll
    for (int s = 32; s > 0; s >>= 1) {
#pragma unroll
        for (int b = 0; b < 4; ++b) acc[b] += __shfl_down(acc[b], s, 64);
    }
    if (lane == 0) {
#pragma unroll
        for (int b = 0; b < 4; ++b) redw[b][wid] = acc[b];
    }
    __syncthreads();
    if (t < 4) {
        float r = redw[t][0] + redw[t][1] + redw[t][2] + redw[t][3];
        rec[(b_base + t) * Pn + p] = r;
    }
}

// ---------------- K3: KL + RE = sum_b max_p rec ; out = mean(KL) - RE ----------------
__global__ void k_final(const float* __restrict__ mu,
                        const float* __restrict__ logstd,
                        const float* __restrict__ eps,
                        const float* __restrict__ ws,
                        float* __restrict__ out) {
    int t = threadIdx.x;   // 128 threads, one per b
    float kl = 0.f;
    for (int l = 0; l < Ln; ++l) {
        int   idx = t * Ln + l;
        float e = eps[idx], ls = logstd[idx];
        float z = mu[idx] + e * __expf(ls);
        kl += -0.5f * e * e - ls + 0.5f * z * z;   // 0.5*log(2pi) cancels
    }
    float m = -INFINITY;
#pragma unroll
    for (int p = 0; p < Pn; p++) m = fmaxf(m, ws[ROFF + t * Pn + p]);
    float contrib = kl * (1.0f / Bn) - m;
    __shared__ float red[128];
    red[t] = contrib;
    __syncthreads();
    for (int s = 64; s > 0; s >>= 1) {
        if (t < s) red[t] += red[t + s];
        __syncthreads();
    }
    if (t == 0) out[0] = red[0];
}

extern "C" void kernel_launch(void* const* d_in, const int* in_sizes, int n_in,
                              void* d_out, int out_size, void* d_ws, size_t ws_size,
                              hipStream_t stream) {
    const float* mu     = (const float*)d_in[0];
    const float* logstd = (const float*)d_in[1];
    const float* eps    = (const float*)d_in[2];
    const float* W      = (const float*)d_in[3];
    const int*   Adj    = (const int*)d_in[4];
    const int*   nm     = (const int*)d_in[5];
    const int*   perms  = (const int*)d_in[6];
    float* ws  = (float*)d_ws;
    float* out = (float*)d_out;

    hipLaunchKernelGGL(k_prep,  dim3(192 + 2 * Pn), dim3(256), 0, stream,
                       mu, logstd, eps, W, Adj, nm, ws);
    hipLaunchKernelGGL(k_main,  dim3(Pn * 32),      dim3(256), 0, stream,
                       perms, ws, ws + ROFF);
    hipLaunchKernelGGL(k_final, dim3(1),            dim3(128), 0, stream,
                       mu, logstd, eps, ws, out);
}

// Round 8
// 115.953 us; speedup vs baseline: 1.1574x; 1.1574x over previous
//
#include <hip/hip_runtime.h>
#include <hip/hip_fp16.h>
#include <math.h>

#define Bn 128
#define Nn 128
#define Ln 64
#define Pn 30
#define PG 10

// ws layout in 4-byte words:
#define TOFF  0        // tab:    [P][N*N] uint32 = half2{logsig(-l), l} : 491520 words
#define BOFF  491520   // Bpack:  [P][N][4] uint32 bitrows of (mask&Adj): 15360 words
#define VOFFW 506880   // validf: [P][N] float                          : 3840 words
#define ROFF  510720   // rec:    [B][P] float                          : 3840 words

// ---------------- K1: table build (GEMM + logsig) + bit-pack ----------------
__global__ __launch_bounds__(256, 4) void k_prep(const float* __restrict__ mu,
                                                 const float* __restrict__ logstd,
                                                 const float* __restrict__ eps,
                                                 const float* __restrict__ W,
                                                 const int* __restrict__ Adj,
                                                 const int* __restrict__ nm,
                                                 float* __restrict__ ws) {
    int blk = blockIdx.x, t = threadIdx.x;
    if (blk < 192) {
        // table blocks: 64 uv-chunks x 3 p-groups of PG=10 graphs
        int chunk = blk & 63, pg = blk >> 6;
        __shared__ float zs[PG][Ln];   // 256B per row -> float4-aligned
        for (int idx = t; idx < PG * Ln; idx += 256) {
            int g = pg * PG * Ln + idx;      // graph index == batch index for b < P
            zs[idx / Ln][idx % Ln] = mu[g] + eps[g] * __expf(logstd[g]);
        }
        __syncthreads();
        int uv = chunk * 256 + t;
        const float* Wp = W + uv;
        float acc[PG];
#pragma unroll
        for (int q = 0; q < PG; q++) acc[q] = 0.f;

        const float4* zs4 = (const float4*)&zs[0][0];   // [PG][16]
        // 4-deep W prefetch; k-block loop NOT unrolled (reg discipline)
        float wv[4];
#pragma unroll
        for (int j = 0; j < 4; ++j) wv[j] = Wp[j * (Nn * Nn)];
#pragma unroll 1
        for (int kb = 0; kb < 16; ++kb) {
            float wc[4];
#pragma unroll
            for (int j = 0; j < 4; ++j) wc[j] = wv[j];
            if (kb < 15) {
#pragma unroll
                for (int j = 0; j < 4; ++j)
                    wv[j] = Wp[((kb + 1) * 4 + j) * (Nn * Nn)];
            }
#pragma unroll
            for (int q = 0; q < PG; q++) {
                float4 z = zs4[q * 16 + kb];
                acc[q] = fmaf(z.x, wc[0], acc[q]);
                acc[q] = fmaf(z.y, wc[1], acc[q]);
                acc[q] = fmaf(z.z, wc[2], acc[q]);
                acc[q] = fmaf(z.w, wc[3], acc[q]);
            }
        }
        uint32_t* tab = (uint32_t*)ws;
#pragma unroll
        for (int q = 0; q < PG; q++) {
            int p = pg * PG + q;
            float l = acc[q];
            float nl = -l;
            float lsneg = (nl < 0.f) ? (nl - log1pf(__expf(nl))) : (-log1pf(__expf(-nl)));
            __half2 h = __floats2half2_rn(lsneg, l);
            tab[p * (Nn * Nn) + uv] = *(uint32_t*)&h;
        }
    } else {
        // bit-pack: 2 blocks per graph, one 32-bit word per thread, no ballot chain
        int pb = blk - 192;
        int p  = pb >> 1;
        int rh = pb & 1;                 // row half: rows rh*64 .. rh*64+63
        __shared__ float    val_s[Nn];
        __shared__ uint32_t vb_s[4];     // valid bits, word w covers cols w*32..+31
        if (t < Nn) {
            float v = (float)nm[p * Nn * Nn + t * Nn + t];  // diag = valid[t]
            val_s[t] = v;
            ws[VOFFW + p * Nn + t] = v;  // both halves write identical values
        }
        __syncthreads();
        if (t < 128) {                   // waves 0,1: wave-uniform branch
            unsigned long long m = __ballot(val_s[t] != 0.f);
            if ((t & 63) == 0) {
                int wv2 = t >> 6;
                vb_s[wv2 * 2]     = (uint32_t)m;
                vb_s[wv2 * 2 + 1] = (uint32_t)(m >> 32);
            }
        }
        __syncthreads();

        int r = t >> 2;                  // local row 0..63
        int w = t & 3;                   // word 0..3
        int i = rh * 64 + r;
        uint32_t bits = 0;
        if (val_s[i] != 0.f) {
            const int4* av = (const int4*)(Adj + p * Nn * Nn + i * Nn + w * 32);
            int4 a[8];
#pragma unroll
            for (int c = 0; c < 8; ++c) a[c] = av[c];   // 8 independent 16B loads
#pragma unroll
            for (int c = 0; c < 8; ++c) {
                bits |= (a[c].x != 0 ? 1u : 0u) << (c * 4 + 0);
                bits |= (a[c].y != 0 ? 1u : 0u) << (c * 4 + 1);
                bits |= (a[c].z != 0 ? 1u : 0u) << (c * 4 + 2);
                bits |= (a[c].w != 0 ? 1u : 0u) << (c * 4 + 3);
            }
            bits &= vb_s[w];
        }
        ((uint32_t*)ws)[BOFF + p * Nn * 4 + i * 4 + w] = bits;
    }
}

// ---------------- K2: hot loop, 4 batches/block, readlane row metadata ----------------
__global__ __launch_bounds__(256) void k_main(const int* __restrict__ perms,
                                              const float* __restrict__ ws,
                                              float* __restrict__ rec) {
    int p  = blockIdx.x >> 5;           // consecutive blocks share per-p data in L2
    int bb = blockIdx.x & 31;
    int b_base = bb * 4;
    int t = threadIdx.x;

    __shared__ int      inv_s[4][Nn];
    __shared__ uint32_t B_s[Nn * 4];
    __shared__ float    valid_s[Nn];
    __shared__ float    redw[4][4];

    // load 4 perms (512 entries) + bits (512 words) + valid (128 floats)
    {
        int idx0 = t, idx1 = t + 256;
        int ba0 = idx0 >> 7, i0 = idx0 & 127;
        int ba1 = idx1 >> 7, i1 = idx1 & 127;
        inv_s[ba0][perms[((b_base + ba0) * Pn + p) * Nn + i0]] = i0;
        inv_s[ba1][perms[((b_base + ba1) * Pn + p) * Nn + i1]] = i1;
        const uint32_t* Bp = (const uint32_t*)ws + BOFF + p * Nn * 4;
        B_s[t]       = Bp[t];
        B_s[256 + t] = Bp[256 + t];
        if (t < Nn) valid_s[t] = ws[VOFFW + p * Nn + t];
    }
    __syncthreads();

    int lane = t & 63;
    int wid  = t >> 6;
    int swid = __builtin_amdgcn_readfirstlane(wid);
    int v0 = 2 * lane, v1 = v0 + 1;

    // loop-invariant per (batch, slot) coordinates + row metadata in registers
    float wv0[4], wv1[4];
    int   a0[4], sh0[4], a1[4], sh1[4];
    int   iu_lo[4], iu_hi[4], vu_lo[4], vu_hi[4];
#pragma unroll
    for (int b = 0; b < 4; ++b) {
        int j0 = inv_s[b][v0], j1 = inv_s[b][v1];
        wv0[b] = valid_s[j0];  wv1[b] = valid_s[j1];
        a0[b] = j0 >> 5; sh0[b] = j0 & 31;
        a1[b] = j1 >> 5; sh1[b] = j1 & 31;
        int il = inv_s[b][lane];       // row metadata: lane L holds row u=L (lo) / 64+L (hi)
        int ih = inv_s[b][64 + lane];
        iu_lo[b] = il; iu_hi[b] = ih;
        vu_lo[b] = __float_as_int(valid_s[il]);
        vu_hi[b] = __float_as_int(valid_s[ih]);
    }

    const uint2* tab2 = (const uint2*)((const uint32_t*)ws + p * (Nn * Nn));
    float acc[4] = {0.f, 0.f, 0.f, 0.f};

    // ---- rows u in [0,64): metadata via readlane from *_lo ----
#pragma unroll
    for (int it = 0; it < 16; ++it) {
        int u = it * 4 + swid;                      // wave-uniform scalar
        uint2 hw = tab2[u * (Nn / 2) + lane];       // coalesced 8B/lane
        float2 f0 = __half22float2(*(__half2*)&hw.x);
        float2 f1 = __half22float2(*(__half2*)&hw.y);
#pragma unroll
        for (int b = 0; b < 4; ++b) {
            int   si  = __builtin_amdgcn_readlane(iu_lo[b], u);
            float swu = __int_as_float(__builtin_amdgcn_readlane(vu_lo[b], u));
            float tmp = fmaf(wv1[b], f1.x, wv0[b] * f0.x);
            acc[b] = fmaf(swu, tmp, acc[b]);
            uint32_t r0 = B_s[si * 4 + a0[b]];
            uint32_t r1 = B_s[si * 4 + a1[b]];
            acc[b] += ((r0 >> sh0[b]) & 1u) ? f0.y : 0.0f;
            acc[b] += ((r1 >> sh1[b]) & 1u) ? f1.y : 0.0f;
        }
    }
    // ---- rows u in [64,128): metadata via readlane from *_hi ----
#pragma unroll
    for (int it = 0; it < 16; ++it) {
        int u = it * 4 + swid;                      // in [0,64): actual row = 64+u
        uint2 hw = tab2[(64 + u) * (Nn / 2) + lane];
        float2 f0 = __half22float2(*(__half2*)&hw.x);
        float2 f1 = __half22float2(*(__half2*)&hw.y);
#pragma unroll
        for (int b = 0; b < 4; ++b) {
            int   si  = __builtin_amdgcn_readlane(iu_hi[b], u);
            float swu = __int_as_float(__builtin_amdgcn_readlane(vu_hi[b], u));
            float tmp = fmaf(wv1[b], f1.x, wv0[b] * f0.x);
            acc[b] = fmaf(swu, tmp, acc[b]);
            uint32_t r0 = B_s[si * 4 + a0[b]];
            uint32_t r1 = B_s[si * 4 + a1[b]];
            acc[b] += ((r0 >> sh0[b]) & 1u) ? f0.y : 0.0f;
            acc[b] += ((r1 >> sh1[b]) & 1u) ? f1.y : 0.0f;
        }
    }

    // wave reduce all 4 accumulators
#pragma unroll
    for (int s = 32; s > 0; s >>= 1) {
#pragma unroll
        for (int b = 0; b < 4; ++b) acc[b] += __shfl_down(acc[b], s, 64);
    }
    if (lane == 0) {
#pragma unroll
        for (int b = 0; b < 4; ++b) redw[b][wid] = acc[b];
    }
    __syncthreads();
    if (t < 4) {
        float r = redw[t][0] + redw[t][1] + redw[t][2] + redw[t][3];
        rec[(b_base + t) * Pn + p] = r;
    }
}

// ---------------- K3: KL + RE = sum_b max_p rec ; out = mean(KL) - RE ----------------
__global__ void k_final(const float* __restrict__ mu,
                        const float* __restrict__ logstd,
                        const float* __restrict__ eps,
                        const float* __restrict__ ws,
                        float* __restrict__ out) {
    int t = threadIdx.x;   // 128 threads, one per b
    float kl = 0.f;
    for (int l = 0; l < Ln; ++l) {
        int   idx = t * Ln + l;
        float e = eps[idx], ls = logstd[idx];
        float z = mu[idx] + e * __expf(ls);
        kl += -0.5f * e * e - ls + 0.5f * z * z;   // 0.5*log(2pi) cancels
    }
    float m = -INFINITY;
#pragma unroll
    for (int p = 0; p < Pn; p++) m = fmaxf(m, ws[ROFF + t * Pn + p]);
    float contrib = kl * (1.0f / Bn) - m;
    __shared__ float red[128];
    red[t] = contrib;
    __syncthreads();
    for (int s = 64; s > 0; s >>= 1) {
        if (t < s) red[t] += red[t + s];
        __syncthreads();
    }
    if (t == 0) out[0] = red[0];
}

extern "C" void kernel_launch(void* const* d_in, const int* in_sizes, int n_in,
                              void* d_out, int out_size, void* d_ws, size_t ws_size,
                              hipStream_t stream) {
    const float* mu     = (const float*)d_in[0];
    const float* logstd = (const float*)d_in[1];
    const float* eps    = (const float*)d_in[2];
    const float* W      = (const float*)d_in[3];
    const int*   Adj    = (const int*)d_in[4];
    const int*   nm     = (const int*)d_in[5];
    const int*   perms  = (const int*)d_in[6];
    float* ws  = (float*)d_ws;
    float* out = (float*)d_out;

    hipLaunchKernelGGL(k_prep,  dim3(192 + 2 * Pn), dim3(256), 0, stream,
                       mu, logstd, eps, W, Adj, nm, ws);
    hipLaunchKernelGGL(k_main,  dim3(Pn * 32),      dim3(256), 0, stream,
                       perms, ws, ws + ROFF);
    hipLaunchKernelGGL(k_final, dim3(1),            dim3(128), 0, stream,
                       mu, logstd, eps, ws, out);
}

// Round 9
// 110.830 us; speedup vs baseline: 1.2109x; 1.0462x over previous
//
#include <hip/hip_runtime.h>
#include <hip/hip_fp16.h>
#include <math.h>

#define Bn 128
#define Nn 128
#define Ln 64
#define Pn 30
#define PG 5   // graphs per GEMM block group (30/PG = 6 groups x 64 chunks = 384 blocks)

// ws layout in 4-byte words:
#define TOFF  0        // tab:    [P][N*N] uint32 = half2{logsig(-l), l} : 491520 words
#define BOFF  491520   // Bpack:  [P][N][4] uint32 bitrows of (mask&Adj): 15360 words
#define VOFFW 506880   // validf: [P][N] float                          : 3840 words
#define ROFF  510720   // rec:    [B][P] float                          : 3840 words

#define GEMM_BLOCKS 384   // (Pn/PG)*64

// ---------------- K1: table build (GEMM + logsig) + bit-pack ----------------
__global__ __launch_bounds__(256, 4) void k_prep(const float* __restrict__ mu,
                                                 const float* __restrict__ logstd,
                                                 const float* __restrict__ eps,
                                                 const float* __restrict__ W,
                                                 const int* __restrict__ Adj,
                                                 const int* __restrict__ nm,
                                                 float* __restrict__ ws) {
    int blk = blockIdx.x, t = threadIdx.x;
    if (blk < GEMM_BLOCKS) {
        // table blocks: 64 uv-chunks x 6 p-groups of PG=5 graphs
        int chunk = blk & 63, pg = blk >> 6;
        __shared__ float zs[PG][Ln];   // 256B per row -> float4-aligned
        for (int idx = t; idx < PG * Ln; idx += 256) {
            int g = pg * PG * Ln + idx;      // graph index == batch index for b < P
            zs[idx / Ln][idx % Ln] = mu[g] + eps[g] * __expf(logstd[g]);
        }
        __syncthreads();
        int uv = chunk * 256 + t;
        const float* Wp = W + uv;
        float acc[PG];
#pragma unroll
        for (int q = 0; q < PG; q++) acc[q] = 0.f;

        const float4* zs4 = (const float4*)&zs[0][0];   // [PG][16]
        // 8-deep W prefetch; k-block loop NOT unrolled (reg discipline)
        float wv[8];
#pragma unroll
        for (int j = 0; j < 8; ++j) wv[j] = Wp[j * (Nn * Nn)];
#pragma unroll 1
        for (int kb = 0; kb < 8; ++kb) {
            float wc[8];
#pragma unroll
            for (int j = 0; j < 8; ++j) wc[j] = wv[j];
            if (kb < 7) {
#pragma unroll
                for (int j = 0; j < 8; ++j)
                    wv[j] = Wp[((kb + 1) * 8 + j) * (Nn * Nn)];
            }
#pragma unroll
            for (int q = 0; q < PG; q++) {
                float4 z0 = zs4[q * 16 + kb * 2];
                float4 z1 = zs4[q * 16 + kb * 2 + 1];
                acc[q] = fmaf(z0.x, wc[0], acc[q]);
                acc[q] = fmaf(z0.y, wc[1], acc[q]);
                acc[q] = fmaf(z0.z, wc[2], acc[q]);
                acc[q] = fmaf(z0.w, wc[3], acc[q]);
                acc[q] = fmaf(z1.x, wc[4], acc[q]);
                acc[q] = fmaf(z1.y, wc[5], acc[q]);
                acc[q] = fmaf(z1.z, wc[6], acc[q]);
                acc[q] = fmaf(z1.w, wc[7], acc[q]);
            }
        }
        uint32_t* tab = (uint32_t*)ws;
#pragma unroll
        for (int q = 0; q < PG; q++) {
            int p = pg * PG + q;
            float l = acc[q];
            float nl = -l;
            float lsneg = (nl < 0.f) ? (nl - log1pf(__expf(nl))) : (-log1pf(__expf(-nl)));
            __half2 h = __floats2half2_rn(lsneg, l);
            tab[p * (Nn * Nn) + uv] = *(uint32_t*)&h;
        }
    } else {
        // bit-pack: 2 blocks per graph, one 32-bit word per thread, no ballot chain
        int pb = blk - GEMM_BLOCKS;
        int p  = pb >> 1;
        int rh = pb & 1;                 // row half: rows rh*64 .. rh*64+63
        __shared__ float    val_s[Nn];
        __shared__ uint32_t vb_s[4];     // valid bits, word w covers cols w*32..+31
        if (t < Nn) {
            float v = (float)nm[p * Nn * Nn + t * Nn + t];  // diag = valid[t]
            val_s[t] = v;
            ws[VOFFW + p * Nn + t] = v;  // both halves write identical values
        }
        __syncthreads();
        if (t < 128) {                   // waves 0,1: wave-uniform branch
            unsigned long long m = __ballot(val_s[t] != 0.f);
            if ((t & 63) == 0) {
                int wv2 = t >> 6;
                vb_s[wv2 * 2]     = (uint32_t)m;
                vb_s[wv2 * 2 + 1] = (uint32_t)(m >> 32);
            }
        }
        __syncthreads();

        int r = t >> 2;                  // local row 0..63
        int w = t & 3;                   // word 0..3
        int i = rh * 64 + r;
        uint32_t bits = 0;
        if (val_s[i] != 0.f) {
            const int4* av = (const int4*)(Adj + p * Nn * Nn + i * Nn + w * 32);
            int4 a[8];
#pragma unroll
            for (int c = 0; c < 8; ++c) a[c] = av[c];   // 8 independent 16B loads
#pragma unroll
            for (int c = 0; c < 8; ++c) {
                bits |= (a[c].x != 0 ? 1u : 0u) << (c * 4 + 0);
                bits |= (a[c].y != 0 ? 1u : 0u) << (c * 4 + 1);
                bits |= (a[c].z != 0 ? 1u : 0u) << (c * 4 + 2);
                bits |= (a[c].w != 0 ? 1u : 0u) << (c * 4 + 3);
            }
            bits &= vb_s[w];
        }
        ((uint32_t*)ws)[BOFF + p * Nn * 4 + i * 4 + w] = bits;
    }
}

// ---------------- K2: hot loop, 4 batches/block, readlane row metadata ----------------
__global__ __launch_bounds__(256) void k_main(const int* __restrict__ perms,
                                              const float* __restrict__ ws,
                                              float* __restrict__ rec) {
    int p  = blockIdx.x >> 5;           // consecutive blocks share per-p data in L2
    int bb = blockIdx.x & 31;
    int b_base = bb * 4;
    int t = threadIdx.x;

    __shared__ int      inv_s[4][Nn];
    __shared__ uint32_t B_s[Nn * 4];
    __shared__ float    valid_s[Nn];
    __shared__ float    redw[4][4];

    // load 4 perms (512 entries) + bits (512 words) + valid (128 floats)
    {
        int idx0 = t, idx1 = t + 256;
        int ba0 = idx0 >> 7, i0 = idx0 & 127;
        int ba1 = idx1 >> 7, i1 = idx1 & 127;
        inv_s[ba0][perms[((b_base + ba0) * Pn + p) * Nn + i0]] = i0;
        inv_s[ba1][perms[((b_base + ba1) * Pn + p) * Nn + i1]] = i1;
        const uint32_t* Bp = (const uint32_t*)ws + BOFF + p * Nn * 4;
        B_s[t]       = Bp[t];
        B_s[256 + t] = Bp[256 + t];
        if (t < Nn) valid_s[t] = ws[VOFFW + p * Nn + t];
    }
    __syncthreads();

    int lane = t & 63;
    int wid  = t >> 6;
    int swid = __builtin_amdgcn_readfirstlane(wid);
    int v0 = 2 * lane, v1 = v0 + 1;

    // loop-invariant per (batch, slot) coordinates + row metadata in registers
    float wv0[4], wv1[4];
    int   a0[4], sh0[4], a1[4], sh1[4];
    int   iu_lo[4], iu_hi[4], vu_lo[4], vu_hi[4];
#pragma unroll
    for (int b = 0; b < 4; ++b) {
        int j0 = inv_s[b][v0], j1 = inv_s[b][v1];
        wv0[b] = valid_s[j0];  wv1[b] = valid_s[j1];
        a0[b] = j0 >> 5; sh0[b] = j0 & 31;
        a1[b] = j1 >> 5; sh1[b] = j1 & 31;
        int il = inv_s[b][lane];       // row metadata: lane L holds row u=L (lo) / 64+L (hi)
        int ih = inv_s[b][64 + lane];
        iu_lo[b] = il; iu_hi[b] = ih;
        vu_lo[b] = __float_as_int(valid_s[il]);
        vu_hi[b] = __float_as_int(valid_s[ih]);
    }

    const uint2* tab2 = (const uint2*)((const uint32_t*)ws + p * (Nn * Nn));
    float acc[4] = {0.f, 0.f, 0.f, 0.f};

    // ---- rows u in [0,64): metadata via readlane from *_lo ----
#pragma unroll
    for (int it = 0; it < 16; ++it) {
        int u = it * 4 + swid;                      // wave-uniform scalar
        uint2 hw = tab2[u * (Nn / 2) + lane];       // coalesced 8B/lane
        float2 f0 = __half22float2(*(__half2*)&hw.x);
        float2 f1 = __half22float2(*(__half2*)&hw.y);
#pragma unroll
        for (int b = 0; b < 4; ++b) {
            int   si  = __builtin_amdgcn_readlane(iu_lo[b], u);
            float swu = __int_as_float(__builtin_amdgcn_readlane(vu_lo[b], u));
            float tmp = fmaf(wv1[b], f1.x, wv0[b] * f0.x);
            acc[b] = fmaf(swu, tmp, acc[b]);
            uint32_t r0 = B_s[si * 4 + a0[b]];
            uint32_t r1 = B_s[si * 4 + a1[b]];
            acc[b] += ((r0 >> sh0[b]) & 1u) ? f0.y : 0.0f;
            acc[b] += ((r1 >> sh1[b]) & 1u) ? f1.y : 0.0f;
        }
    }
    // ---- rows u in [64,128): metadata via readlane from *_hi ----
#pragma unroll
    for (int it = 0; it < 16; ++it) {
        int u = it * 4 + swid;                      // in [0,64): actual row = 64+u
        uint2 hw = tab2[(64 + u) * (Nn / 2) + lane];
        float2 f0 = __half22float2(*(__half2*)&hw.x);
        float2 f1 = __half22float2(*(__half2*)&hw.y);
#pragma unroll
        for (int b = 0; b < 4; ++b) {
            int   si  = __builtin_amdgcn_readlane(iu_hi[b], u);
            float swu = __int_as_float(__builtin_amdgcn_readlane(vu_hi[b], u));
            float tmp = fmaf(wv1[b], f1.x, wv0[b] * f0.x);
            acc[b] = fmaf(swu, tmp, acc[b]);
            uint32_t r0 = B_s[si * 4 + a0[b]];
            uint32_t r1 = B_s[si * 4 + a1[b]];
            acc[b] += ((r0 >> sh0[b]) & 1u) ? f0.y : 0.0f;
            acc[b] += ((r1 >> sh1[b]) & 1u) ? f1.y : 0.0f;
        }
    }

    // wave reduce all 4 accumulators
#pragma unroll
    for (int s = 32; s > 0; s >>= 1) {
#pragma unroll
        for (int b = 0; b < 4; ++b) acc[b] += __shfl_down(acc[b], s, 64);
    }
    if (lane == 0) {
#pragma unroll
        for (int b = 0; b < 4; ++b) redw[b][wid] = acc[b];
    }
    __syncthreads();
    if (t < 4) {
        float r = redw[t][0] + redw[t][1] + redw[t][2] + redw[t][3];
        rec[(b_base + t) * Pn + p] = r;
    }
}

// ---------------- K3: KL + RE = sum_b max_p rec ; out = mean(KL) - RE ----------------
__global__ void k_final(const float* __restrict__ mu,
                        const float* __restrict__ logstd,
                        const float* __restrict__ eps,
                        const float* __restrict__ ws,
                        float* __restrict__ out) {
    int t = threadIdx.x;   // 128 threads, one per b
    const float4* mu4 = (const float4*)(mu     + t * Ln);
    const float4* ls4 = (const float4*)(logstd + t * Ln);
    const float4* ep4 = (const float4*)(eps    + t * Ln);
    float kl = 0.f;
#pragma unroll
    for (int l4 = 0; l4 < Ln / 4; ++l4) {
        float4 m = mu4[l4], ls = ls4[l4], e = ep4[l4];
        float z0 = m.x + e.x * __expf(ls.x);
        float z1 = m.y + e.y * __expf(ls.y);
        float z2 = m.z + e.z * __expf(ls.z);
        float z3 = m.w + e.w * __expf(ls.w);
        kl += -0.5f * e.x * e.x - ls.x + 0.5f * z0 * z0;
        kl += -0.5f * e.y * e.y - ls.y + 0.5f * z1 * z1;
        kl += -0.5f * e.z * e.z - ls.z + 0.5f * z2 * z2;
        kl += -0.5f * e.w * e.w - ls.w + 0.5f * z3 * z3;
    }
    float m = -INFINITY;
#pragma unroll
    for (int p = 0; p < Pn; p++) m = fmaxf(m, ws[ROFF + t * Pn + p]);
    float contrib = kl * (1.0f / Bn) - m;
    __shared__ float red[128];
    red[t] = contrib;
    __syncthreads();
    for (int s = 64; s > 0; s >>= 1) {
        if (t < s) red[t] += red[t + s];
        __syncthreads();
    }
    if (t == 0) out[0] = red[0];
}

extern "C" void kernel_launch(void* const* d_in, const int* in_sizes, int n_in,
                              void* d_out, int out_size, void* d_ws, size_t ws_size,
                              hipStream_t stream) {
    const float* mu     = (const float*)d_in[0];
    const float* logstd = (const float*)d_in[1];
    const float* eps    = (const float*)d_in[2];
    const float* W      = (const float*)d_in[3];
    const int*   Adj    = (const int*)d_in[4];
    const int*   nm     = (const int*)d_in[5];
    const int*   perms  = (const int*)d_in[6];
    float* ws  = (float*)d_ws;
    float* out = (float*)d_out;

    hipLaunchKernelGGL(k_prep,  dim3(GEMM_BLOCKS + 2 * Pn), dim3(256), 0, stream,
                       mu, logstd, eps, W, Adj, nm, ws);
    hipLaunchKernelGGL(k_main,  dim3(Pn * 32),              dim3(256), 0, stream,
                       perms, ws, ws + ROFF);
    hipLaunchKernelGGL(k_final, dim3(1),                    dim3(128), 0, stream,
                       mu, logstd, eps, ws, out);
}